// Round 4
// baseline (204.044 us; speedup 1.0000x reference)
//
#include <hip/hip_runtime.h>
#include <hip/hip_bf16.h>

#define B_ 4096
#define N_ 64
#define D_ 128
#define H_ 2
#define M_ 384
#define DK_ 192
#define NB 8
#define SROW 388   // padded f32 row stride for skb

// ws float offsets
#define WS_WKEFF 64
#define WS_W1T   1024
#define WS_W2T   66560
#define WS_CTX   82944
#define WS_OUTV  (WS_CTX + B_ * (H_ * M_))
#define WS_R     (WS_OUTV + B_ * M_)
#define WS_TOTAL (WS_R + B_ * M_)

// ---------------------------------------------------------------- prep: mask probe + wk_eff + W1^T/W2^T
__global__ __launch_bounds__(256) void prep2(
    const float* __restrict__ Wk, const float* __restrict__ wmap,
    const float* __restrict__ W1, const float* __restrict__ W2,
    const void* __restrict__ mask, int* __restrict__ flag,
    float* __restrict__ wkeff, float* __restrict__ W1t, float* __restrict__ W2t) {
    const int tid = threadIdx.x;
    if (blockIdx.x == 0 && tid == 0) {
        const unsigned int* u = (const unsigned int*)mask;
        bool all01 = true, allf = true;
        for (int i = 0; i < 64; ++i) {
            unsigned int v = u[i];
            if (v != 0u && v != 1u) all01 = false;
            if (v != 0u && v != 0x3f800000u) allf = false;
        }
        *flag = all01 ? 0 : (allf ? 2 : 1);
    }
    const int lane = tid & 63, wave = tid >> 6;
    const int gw = blockIdx.x * 4 + wave;
    if (gw < H_ * M_) {
        const int h = gw / M_, m = gw - h * M_;
        float s = 0.f;
        #pragma unroll
        for (int i = 0; i < 3; ++i) {
            int d = lane + i * 64;
            s += wmap[DK_ + d] * Wk[(size_t)(h * DK_ + d) * M_ + m];
        }
        #pragma unroll
        for (int off = 1; off < 64; off <<= 1) s += __shfl_xor(s, off, 64);
        if (lane == 0) wkeff[gw] = s;
    }
    const int gt = blockIdx.x * 256 + tid;
    const int stride = gridDim.x * 256;
    for (int i = gt; i < (M_ + D_) * D_; i += stride) {
        int k = i >> 7, o = i & 127;
        W1t[i] = W1[(size_t)o * (M_ + D_) + k];
    }
    for (int i = gt; i < D_ * D_; i += stride) {
        int k = i >> 7, o = i & 127;
        W2t[i] = W2[(size_t)o * D_ + k];
    }
}

// ---------------------------------------------------------------- persistent pipelined attention
// 512 blocks x 512 threads; each block streams NB=8 batches.
// pipeline: {softmax(b) || issue loads(b+1)} -> bar -> ctx(b) -> bar -> consume(b+1) -> bar
__global__ __launch_bounds__(512, 2) void attn_pipe(
    const float* __restrict__ seq, const float* __restrict__ seqE,
    const float* __restrict__ seqT, const void* __restrict__ mask,
    const float* __restrict__ wkeff, const int* __restrict__ flagp,
    float* __restrict__ ctx, float* __restrict__ attn_out) {
    __shared__ float skb[N_ * SROW];   // 99328 B
    __shared__ float slog[H_ * N_];

    const int tid = threadIdx.x;
    const int lane = tid & 63;
    const int j8 = tid & 15;
    const int b0 = blockIdx.x * NB;
    const int flag = *flagp;

    // wkeff in registers
    float wr[2][3][8];
    #pragma unroll
    for (int h = 0; h < 2; ++h)
        #pragma unroll
        for (int t = 0; t < 3; ++t) {
            float4 wa = *(const float4*)&wkeff[h * M_ + t * 128 + j8 * 8];
            float4 wb = *(const float4*)&wkeff[h * M_ + t * 128 + j8 * 8 + 4];
            wr[h][t][0] = wa.x; wr[h][t][1] = wa.y; wr[h][t][2] = wa.z; wr[h][t][3] = wa.w;
            wr[h][t][4] = wb.x; wr[h][t][5] = wb.y; wr[h][t][6] = wb.z; wr[h][t][7] = wb.w;
        }

    float4 pf[12];   // prefetch registers: 2 k2 x 3 arrays x 2 float4

#define ISSUE(bb) do {                                                        \
    const size_t obase_ = (size_t)(bb) * (N_ * D_);                           \
    _Pragma("unroll")                                                         \
    for (int k2 = 0; k2 < 2; ++k2) {                                          \
        const size_t off_ = obase_ + (size_t)(k2 * 512 + tid) * 8;            \
        pf[k2*6+0] = *(const float4*)&seq [off_];                             \
        pf[k2*6+1] = *(const float4*)&seq [off_ + 4];                         \
        pf[k2*6+2] = *(const float4*)&seqE[off_];                             \
        pf[k2*6+3] = *(const float4*)&seqE[off_ + 4];                         \
        pf[k2*6+4] = *(const float4*)&seqT[off_];                             \
        pf[k2*6+5] = *(const float4*)&seqT[off_ + 4];                         \
    } } while (0)

#define CONSUME() do {                                                        \
    _Pragma("unroll")                                                         \
    for (int k2 = 0; k2 < 2; ++k2) {                                          \
        const int n_ = (k2 * 512 + tid) >> 4;                                 \
        float a0_ = 0.f, a1_ = 0.f;                                           \
        _Pragma("unroll")                                                     \
        for (int t = 0; t < 3; ++t) {                                         \
            float4 v0 = pf[k2*6 + t*2], v1 = pf[k2*6 + t*2 + 1];              \
            a0_ += v0.x*wr[0][t][0] + v0.y*wr[0][t][1] + v0.z*wr[0][t][2]     \
                 + v0.w*wr[0][t][3] + v1.x*wr[0][t][4] + v1.y*wr[0][t][5]     \
                 + v1.z*wr[0][t][6] + v1.w*wr[0][t][7];                       \
            a1_ += v0.x*wr[1][t][0] + v0.y*wr[1][t][1] + v0.z*wr[1][t][2]     \
                 + v0.w*wr[1][t][3] + v1.x*wr[1][t][4] + v1.y*wr[1][t][5]     \
                 + v1.z*wr[1][t][6] + v1.w*wr[1][t][7];                       \
            *(float4*)&skb[n_ * SROW + t * 128 + j8 * 8]     = v0;            \
            *(float4*)&skb[n_ * SROW + t * 128 + j8 * 8 + 4] = v1;            \
        }                                                                     \
        _Pragma("unroll")                                                     \
        for (int off = 1; off < 16; off <<= 1) {                              \
            a0_ += __shfl_xor(a0_, off, 64);                                  \
            a1_ += __shfl_xor(a1_, off, 64);                                  \
        }                                                                     \
        if ((lane & 15) == 0) { slog[n_] = a0_; slog[64 + n_] = a1_; }        \
    } } while (0)

    // prologue
    ISSUE(b0);
    CONSUME();
    __syncthreads();

    for (int bi = 0; bi < NB; ++bi) {
        const int b = b0 + bi;

        // softmax (2 waves) — probabilities written back into slog
        if (tid < H_ * N_) {
            const int h = tid >> 6, n = tid & 63;
            float lg = slog[tid];
            int mv;
            if (flag == 0)      mv = ((const int*)mask)[(size_t)b * N_ + n];
            else if (flag == 1) mv = ((const unsigned char*)mask)[(size_t)b * N_ + n];
            else                mv = (((const unsigned int*)mask)[(size_t)b * N_ + n] != 0u) ? 1 : 0;
            if (mv) lg = -INFINITY;
            float mx = lg;
            #pragma unroll
            for (int off = 32; off > 0; off >>= 1) mx = fmaxf(mx, __shfl_xor(mx, off, 64));
            float e = __expf(lg - mx);
            float s = e;
            #pragma unroll
            for (int off = 32; off > 0; off >>= 1) s += __shfl_xor(s, off, 64);
            float a = e / s;
            slog[tid] = a;
            attn_out[((size_t)h * B_ + b) * N_ + n] = a;
        }
        if (bi + 1 < NB) ISSUE(b + 1);   // loads stay in flight across barriers
        __syncthreads();

        // ctx(b): 384 threads; (u,q) = (output 8-chunk, 4-way n split)
        if (tid < 384) {
            const int u = tid >> 2, q = tid & 3;
            const int h = (u >= 48) ? 1 : 0;
            const int m8 = u - h * 48;
            const float* pr = &slog[h * 64];
            float acc[8] = {};
            #pragma unroll
            for (int i = 0; i < 16; ++i) {
                const int n = q * 16 + ((i + q) & 15);
                const float a = pr[n];
                float4 k0 = *(const float4*)&skb[n * SROW + m8 * 8];
                float4 k1 = *(const float4*)&skb[n * SROW + m8 * 8 + 4];
                acc[0] += a * k0.x; acc[1] += a * k0.y; acc[2] += a * k0.z; acc[3] += a * k0.w;
                acc[4] += a * k1.x; acc[5] += a * k1.y; acc[6] += a * k1.z; acc[7] += a * k1.w;
            }
            #pragma unroll
            for (int off = 1; off < 4; off <<= 1)
                #pragma unroll
                for (int j = 0; j < 8; ++j) acc[j] += __shfl_xor(acc[j], off, 64);
            if (q == 0) {
                float* cp = &ctx[(size_t)b * (H_ * M_) + h * M_ + m8 * 8];
                *(float4*)cp       = make_float4(acc[0], acc[1], acc[2], acc[3]);
                *(float4*)(cp + 4) = make_float4(acc[4], acc[5], acc[6], acc[7]);
            }
        }
        __syncthreads();

        if (bi + 1 < NB) CONSUME();      // overwrite skb, write slog for b+1
        __syncthreads();
    }
#undef ISSUE
#undef CONSUME
}

// ---------------------------------------------------------------- GEMM: out_v = ctx_h @ Wv_h^T  (BK=32)
__global__ __launch_bounds__(256) void gemm_v(
    const float* __restrict__ ctx, const float* __restrict__ Wv, float* __restrict__ outv) {
    __shared__ float sA[32 * 68], sB[32 * 68];
    const int j0 = blockIdx.x * 64;
    const int b0 = blockIdx.y * 64;
    const int aOff = (j0 >= DK_) ? M_ : 0;
    const int tid = threadIdx.x;
    const int tx = tid & 15, ty = tid >> 4;
    const int lr = tid >> 2, lc = (tid & 3) * 8;
    float acc[4][4] = {};
    for (int kk = 0; kk < M_; kk += 32) {
        float4 va  = *(const float4*)&ctx[(size_t)(b0 + lr) * (H_ * M_) + aOff + kk + lc];
        float4 va2 = *(const float4*)&ctx[(size_t)(b0 + lr) * (H_ * M_) + aOff + kk + lc + 4];
        float4 vb  = *(const float4*)&Wv[(size_t)(j0 + lr) * M_ + kk + lc];
        float4 vb2 = *(const float4*)&Wv[(size_t)(j0 + lr) * M_ + kk + lc + 4];
        __syncthreads();
        sA[(lc + 0) * 68 + lr] = va.x;  sA[(lc + 1) * 68 + lr] = va.y;
        sA[(lc + 2) * 68 + lr] = va.z;  sA[(lc + 3) * 68 + lr] = va.w;
        sA[(lc + 4) * 68 + lr] = va2.x; sA[(lc + 5) * 68 + lr] = va2.y;
        sA[(lc + 6) * 68 + lr] = va2.z; sA[(lc + 7) * 68 + lr] = va2.w;
        sB[(lc + 0) * 68 + lr] = vb.x;  sB[(lc + 1) * 68 + lr] = vb.y;
        sB[(lc + 2) * 68 + lr] = vb.z;  sB[(lc + 3) * 68 + lr] = vb.w;
        sB[(lc + 4) * 68 + lr] = vb2.x; sB[(lc + 5) * 68 + lr] = vb2.y;
        sB[(lc + 6) * 68 + lr] = vb2.z; sB[(lc + 7) * 68 + lr] = vb2.w;
        __syncthreads();
        #pragma unroll
        for (int k = 0; k < 32; ++k) {
            float a[4], bb[4];
            *(float4*)a  = *(const float4*)&sA[k * 68 + ty * 4];
            *(float4*)bb = *(const float4*)&sB[k * 68 + tx * 4];
            #pragma unroll
            for (int r = 0; r < 4; ++r)
                #pragma unroll
                for (int c = 0; c < 4; ++c) acc[r][c] += a[r] * bb[c];
        }
    }
    #pragma unroll
    for (int r = 0; r < 4; ++r)
        *(float4*)&outv[(size_t)(b0 + ty * 4 + r) * M_ + j0 + tx * 4] =
            make_float4(acc[r][0], acc[r][1], acc[r][2], acc[r][3]);
}

// ---------------------------------------------------------------- GEMM: fc + leaky + residual (BK=32)
__global__ __launch_bounds__(256) void gemm_fc(
    const float* __restrict__ A, const float* __restrict__ Wfc, const float* __restrict__ bfc,
    const float* __restrict__ src, const float* __restrict__ src_s, const float* __restrict__ src_t,
    float* __restrict__ rws) {
    __shared__ float sA[32 * 68], sB[32 * 68];
    const int j0 = blockIdx.x * 64;
    const int b0 = blockIdx.y * 64;
    const int tid = threadIdx.x;
    const int tx = tid & 15, ty = tid >> 4;
    const int lr = tid >> 2, lc = (tid & 3) * 8;
    float acc[4][4] = {};
    for (int kk = 0; kk < M_; kk += 32) {
        float4 va  = *(const float4*)&A[(size_t)(b0 + lr) * M_ + kk + lc];
        float4 va2 = *(const float4*)&A[(size_t)(b0 + lr) * M_ + kk + lc + 4];
        float4 vb  = *(const float4*)&Wfc[(size_t)(j0 + lr) * M_ + kk + lc];
        float4 vb2 = *(const float4*)&Wfc[(size_t)(j0 + lr) * M_ + kk + lc + 4];
        __syncthreads();
        sA[(lc + 0) * 68 + lr] = va.x;  sA[(lc + 1) * 68 + lr] = va.y;
        sA[(lc + 2) * 68 + lr] = va.z;  sA[(lc + 3) * 68 + lr] = va.w;
        sA[(lc + 4) * 68 + lr] = va2.x; sA[(lc + 5) * 68 + lr] = va2.y;
        sA[(lc + 6) * 68 + lr] = va2.z; sA[(lc + 7) * 68 + lr] = va2.w;
        sB[(lc + 0) * 68 + lr] = vb.x;  sB[(lc + 1) * 68 + lr] = vb.y;
        sB[(lc + 2) * 68 + lr] = vb.z;  sB[(lc + 3) * 68 + lr] = vb.w;
        sB[(lc + 4) * 68 + lr] = vb2.x; sB[(lc + 5) * 68 + lr] = vb2.y;
        sB[(lc + 6) * 68 + lr] = vb2.z; sB[(lc + 7) * 68 + lr] = vb2.w;
        __syncthreads();
        #pragma unroll
        for (int k = 0; k < 32; ++k) {
            float a[4], bb[4];
            *(float4*)a  = *(const float4*)&sA[k * 68 + ty * 4];
            *(float4*)bb = *(const float4*)&sB[k * 68 + tx * 4];
            #pragma unroll
            for (int r = 0; r < 4; ++r)
                #pragma unroll
                for (int c = 0; c < 4; ++c) acc[r][c] += a[r] * bb[c];
        }
    }
    const float* qsrc = (j0 < D_) ? src : (j0 < 2 * D_) ? src_s : src_t;
    const int joff = j0 % D_;
    #pragma unroll
    for (int r = 0; r < 4; ++r) {
        int i = b0 + ty * 4 + r;
        float4 qv = *(const float4*)&qsrc[(size_t)i * D_ + joff + tx * 4];
        float q[4] = {qv.x, qv.y, qv.z, qv.w};
        float res[4];
        #pragma unroll
        for (int c = 0; c < 4; ++c) {
            int j = j0 + tx * 4 + c;
            float t = acc[r][c] + bfc[j];
            t = t > 0.f ? t : 0.2f * t;
            res[c] = t + q[c];
        }
        *(float4*)&rws[(size_t)i * M_ + j0 + tx * 4] = make_float4(res[0], res[1], res[2], res[3]);
    }
}

// ---------------------------------------------------------------- LayerNorm + MLP (8 rows/block, 512 blocks)
__global__ __launch_bounds__(256) void ln_mlp(
    const float* __restrict__ rin, const float* __restrict__ src,
    const float* __restrict__ g, const float* __restrict__ bta,
    const float* __restrict__ W1t, const float* __restrict__ b1,
    const float* __restrict__ W2t, const float* __restrict__ b2,
    float* __restrict__ outp) {
    __shared__ float sa[8 * 520];
    __shared__ float sh[8 * 132];
    const int b0 = blockIdx.x * 8;
    const int tid = threadIdx.x;
    const int row = tid >> 5, part = tid & 31;
    const size_t gr = (size_t)(b0 + row);
    {
        const float* rr = &rin[gr * M_];
        float4 v[3];
        float s = 0.f, sq = 0.f;
        #pragma unroll
        for (int i = 0; i < 3; ++i) {
            v[i] = *(const float4*)&rr[(part + i * 32) * 4];
            s  += v[i].x + v[i].y + v[i].z + v[i].w;
            sq += v[i].x * v[i].x + v[i].y * v[i].y + v[i].z * v[i].z + v[i].w * v[i].w;
        }
        #pragma unroll
        for (int off = 1; off < 32; off <<= 1) {
            s += __shfl_xor(s, off, 64); sq += __shfl_xor(sq, off, 64);
        }
        float mu = s * (1.f / 384.f);
        float rs = rsqrtf(sq * (1.f / 384.f) - mu * mu + 1e-5f);
        #pragma unroll
        for (int i = 0; i < 3; ++i) {
            int k = (part + i * 32) * 4;
            float4 g4 = *(const float4*)&g[k];
            float4 b4 = *(const float4*)&bta[k];
            float4 z;
            z.x = (v[i].x - mu) * rs * g4.x + b4.x;
            z.y = (v[i].y - mu) * rs * g4.y + b4.y;
            z.z = (v[i].z - mu) * rs * g4.z + b4.z;
            z.w = (v[i].w - mu) * rs * g4.w + b4.w;
            *(float4*)&sa[row * 520 + k] = z;
        }
        *(float4*)&sa[row * 520 + M_ + part * 4] = *(const float4*)&src[gr * D_ + part * 4];
    }
    __syncthreads();
    const int c4 = part * 4;
    float acc[4] = {};
    const float* ar = &sa[row * 520];
    #pragma unroll 4
    for (int k4 = 0; k4 < 128; ++k4) {
        float4 a4 = *(const float4*)&ar[k4 * 4];
        #pragma unroll
        for (int j = 0; j < 4; ++j) {
            int k = k4 * 4 + j;
            float a = (j == 0) ? a4.x : (j == 1) ? a4.y : (j == 2) ? a4.z : a4.w;
            float4 w = *(const float4*)&W1t[k * D_ + c4];
            acc[0] += a * w.x; acc[1] += a * w.y; acc[2] += a * w.z; acc[3] += a * w.w;
        }
    }
    {
        float4 bb = *(const float4*)&b1[c4];
        float4 hh;
        hh.x = fmaxf(acc[0] + bb.x, 0.f);
        hh.y = fmaxf(acc[1] + bb.y, 0.f);
        hh.z = fmaxf(acc[2] + bb.z, 0.f);
        hh.w = fmaxf(acc[3] + bb.w, 0.f);
        *(float4*)&sh[row * 132 + c4] = hh;
    }
    __syncthreads();
    float acc2[4] = {};
    const float* hr = &sh[row * 132];
    #pragma unroll 4
    for (int k4 = 0; k4 < 32; ++k4) {
        float4 a4 = *(const float4*)&hr[k4 * 4];
        #pragma unroll
        for (int j = 0; j < 4; ++j) {
            int k = k4 * 4 + j;
            float a = (j == 0) ? a4.x : (j == 1) ? a4.y : (j == 2) ? a4.z : a4.w;
            float4 w = *(const float4*)&W2t[k * D_ + c4];
            acc2[0] += a * w.x; acc2[1] += a * w.y; acc2[2] += a * w.z; acc2[3] += a * w.w;
        }
    }
    float4 bb2 = *(const float4*)&b2[c4];
    float4 oo = make_float4(acc2[0] + bb2.x, acc2[1] + bb2.y, acc2[2] + bb2.z, acc2[3] + bb2.w);
    *(float4*)&outp[gr * D_ + c4] = oo;
}

// ---------------------------------------------------------------- launcher
extern "C" void kernel_launch(void* const* d_in, const int* in_sizes, int n_in,
                              void* d_out, int out_size, void* d_ws, size_t ws_size,
                              hipStream_t stream) {
    (void)in_sizes; (void)n_in; (void)out_size;
    const float* src   = (const float*)d_in[0];
    const float* src_t = (const float*)d_in[1];
    const float* src_s = (const float*)d_in[2];
    const float* seq   = (const float*)d_in[3];
    const float* seq_t = (const float*)d_in[4];
    const float* seq_e = (const float*)d_in[5];
    const void*  mask  = d_in[6];
    // d_in[7] = Wq: unused (cancels in softmax)
    const float* Wk    = (const float*)d_in[8];
    const float* Wv    = (const float*)d_in[9];
    const float* wmap  = (const float*)d_in[10];
    const float* Wfc   = (const float*)d_in[11];
    const float* bfc   = (const float*)d_in[12];
    const float* ln_g  = (const float*)d_in[13];
    const float* ln_b  = (const float*)d_in[14];
    const float* W1    = (const float*)d_in[15];
    const float* b1    = (const float*)d_in[16];
    const float* W2    = (const float*)d_in[17];
    const float* b2    = (const float*)d_in[18];

    if (ws_size < (size_t)WS_TOTAL * sizeof(float)) return;
    float* wsf   = (float*)d_ws;
    int*   flagp = (int*)d_ws;           // ws[0..15] reserved
    float* wkeff = wsf + WS_WKEFF;
    float* W1t   = wsf + WS_W1T;
    float* W2t   = wsf + WS_W2T;
    float* ctx   = wsf + WS_CTX;
    float* outv  = wsf + WS_OUTV;
    float* rws   = wsf + WS_R;
    float* outp     = (float*)d_out;
    float* attn_out = outp + (size_t)B_ * D_;

    prep2<<<256, 256, 0, stream>>>(Wk, wmap, W1, W2, mask, flagp, wkeff, W1t, W2t);
    attn_pipe<<<B_ / NB, 512, 0, stream>>>(seq, seq_e, seq_t, mask, wkeff, flagp, ctx, attn_out);
    gemm_v<<<dim3(6, 64), 256, 0, stream>>>(ctx, Wv, outv);
    gemm_fc<<<dim3(6, 64), 256, 0, stream>>>(outv, Wfc, bfc, src, src_s, src_t, rws);
    ln_mlp<<<512, 256, 0, stream>>>(rws, src, ln_g, ln_b, W1t, b1, W2t, b2, outp);
}